// Round 16
// baseline (517.311 us; speedup 1.0000x reference)
//
#include <hip/hip_runtime.h>
#include <hip/hip_bf16.h>

typedef __attribute__((ext_vector_type(8))) short bf16x8;
typedef __attribute__((ext_vector_type(4))) float f32x4;

#define GLD16(g, s) __builtin_amdgcn_global_load_lds( \
    (const __attribute__((address_space(1))) void*)(g), \
    (__attribute__((address_space(3))) void*)(s), 16, 0, 0)

#define SBAR() __builtin_amdgcn_sched_barrier(0)
#define WAIT_LGKM(n) do { asm volatile("s_waitcnt lgkmcnt(" #n ")" ::: "memory"); SBAR(); } while (0)

static constexpr int kB  = 128;
static constexpr int kC  = 1280;
static constexpr int kHW = 256;

__device__ __forceinline__ float bf2f(unsigned short u) {
    return __uint_as_float(((unsigned int)u) << 16);
}

// R16 GEMM: BM=BN=256, BK=32; 512 thr = 8 waves (2M x 4N), wave tile 128x64,
// MFMA 16x16x32 (one K-step per tile). 4 LDS slots x 32KB, depth-3 tile
// prefetch. Per K-tile: vmcnt(8 counted, never 0 in steady state) + ONE
// barrier + 12 ds_reads + 4 glds (t+3) + lgkm(4)/lgkm(0) interleaved MFMA.
// BK=32 rows (64B): fragment reads are 2-way bank aliases (free, m136) ->
// NO swizzle, linear staging. Slot (t+3)&3 reuse proven safe by the top
// barrier (all waves' t-1 reads retired before it).
// OUT_MODE: 0=bf16 rowmajor, 1=f32 rowmajor, 2=bf16 conv (col=(b,pix)),
//           3=f32 conv alpha*(acc+bias)+resid, 4=f32 conv-by-z PV epilogue
// BIAS_MODE: 0=none, 1=bias[col], 2=bias[row]
// ORDER: 0 = m-fastest (B operand large), 1 = n-fastest (A operand large)
template<int OUT_MODE, int BIAS_MODE, int ORDER>
__device__ __forceinline__ void gemm_body(
    const __hip_bfloat16* __restrict__ A,
    const __hip_bfloat16* __restrict__ Bt,
    void* __restrict__ outp,
    const float* __restrict__ bias,
    const float* __restrict__ resid,
    const float* __restrict__ alphap,
    const float* __restrict__ aux1,
    const float* __restrict__ aux2,
    int M, int N, int K,
    int ldA, int ldB, long sA, long sB, long sC, int ldC,
    char* smem, int z)
{
    const int t = threadIdx.x;
    const int w = t >> 6, l = t & 63;
    const int q = l >> 4, r16 = l & 15;
    const int wr = w >> 2, wc = w & 3;   // 2M x 4N waves
    const int nbm = M >> 8, nbn = N >> 8;
    const int nwg = nbm * nbn;
    int f = blockIdx.x;
    {   // bijective XCD swizzle (m204)
        const int q8 = nwg >> 3, r8 = nwg & 7;
        const int xcd = f & 7, rank = f >> 3;
        f = (xcd < r8 ? xcd * (q8 + 1) : r8 * (q8 + 1) + (xcd - r8) * q8) + rank;
    }
    long m0, n0;
    if (ORDER == 0) { m0 = (long)(f % nbm) << 8; n0 = (long)(f / nbm) << 8; }
    else            { n0 = (long)(f % nbn) << 8; m0 = (long)(f / nbn) << 8; }
    const char* Azb = (const char*)(A + (long)z * sA);
    const char* Bzb = (const char*)(Bt + (long)z * sB);

    // staging addresses: BK=32 -> 64B rows; advance +64B per K-tile; LINEAR
    const char* pa[2];
    const char* pb[2];
    int ldsd[2];
    #pragma unroll
    for (int i = 0; i < 2; ++i) {
        const int d = i * 8192 + t * 16;
        const int row = d >> 6;            // 64B per row
        const int col = d & 63;
        pa[i] = Azb + ((m0 + row) * (long)ldA) * 2 + col;
        pb[i] = Bzb + ((n0 + row) * (long)ldB) * 2 + col;
        ldsd[i] = d;
    }
    auto stage = [&](int slot) {
        char* base = smem + slot * 32768;  // A 16KB + B 16KB
        GLD16(pa[0], base + ldsd[0]);
        GLD16(pa[1], base + ldsd[1]);
        GLD16(pb[0], base + 16384 + ldsd[0]);
        GLD16(pb[1], base + 16384 + ldsd[1]);
        pa[0] += 64; pa[1] += 64; pb[0] += 64; pb[1] += 64;
    };

    // LDS read offsets: addr = (rowbase + r16)*64 + q*16  (+ blk*1024)
    const int aoff = (wr * 128 + r16) * 64 + q * 16;
    const int boff = 16384 + (wc * 64 + r16) * 64 + q * 16;

#define DSA(dst, bs_, mih) do { const char* p_ = (bs_) + aoff + (mih) * 4096; \
    dst[0] = *(const bf16x8*)(p_);        dst[1] = *(const bf16x8*)(p_ + 1024); \
    dst[2] = *(const bf16x8*)(p_ + 2048); dst[3] = *(const bf16x8*)(p_ + 3072); } while (0)
#define DSB(dst, bs_) do { const char* p_ = (bs_) + boff; \
    dst[0] = *(const bf16x8*)(p_);        dst[1] = *(const bf16x8*)(p_ + 1024); \
    dst[2] = *(const bf16x8*)(p_ + 2048); dst[3] = *(const bf16x8*)(p_ + 3072); } while (0)
#define MM16(ar, br, mih) do { __builtin_amdgcn_s_setprio(1); \
    _Pragma("unroll") for (int j = 0; j < 4; ++j) \
    _Pragma("unroll") for (int ni = 0; ni < 4; ++ni) \
        acc[(mih) * 4 + j][ni] = __builtin_amdgcn_mfma_f32_16x16x32_bf16( \
            ar[j], br[ni], acc[(mih) * 4 + j][ni], 0, 0, 0); \
    __builtin_amdgcn_s_setprio(0); SBAR(); } while (0)

    f32x4 acc[8][4] = {};
    const int nK = K >> 5;

    stage(0);
    if (nK > 1) stage(1);
    if (nK > 2) stage(2);

    for (int tk = 0; tk < nK; ++tk) {
        // counted wait: outstanding = loads of t+1,t+2 (8); tile t's own
        // loads (issued 3 tiles ago) are the oldest and must retire.
        const int rem = nK - 1 - tk;
        if (rem >= 2)      { asm volatile("s_waitcnt vmcnt(8)" ::: "memory"); }
        else if (rem == 1) { asm volatile("s_waitcnt vmcnt(4)" ::: "memory"); }
        else               { asm volatile("s_waitcnt vmcnt(0)" ::: "memory"); }
        SBAR();
        __builtin_amdgcn_s_barrier();   // tile t visible; slot (t+3)&3 free
        SBAR();

        const char* bs_ = smem + (tk & 3) * 32768;
        bf16x8 a0[4], a1[4], b0[4];
        DSB(b0, bs_);
        DSA(a0, bs_, 0);
        DSA(a1, bs_, 1);
        if (tk + 3 < nK) stage((tk + 3) & 3);
        SBAR();
        WAIT_LGKM(4);   // b0 + a0 ready (a1 in flight)
        MM16(a0, b0, 0);
        WAIT_LGKM(0);   // a1 ready
        MM16(a1, b0, 1);
    }

    const float alpha = (OUT_MODE >= 3) ? alphap[0] : 0.0f;
    #pragma unroll
    for (int mi = 0; mi < 8; ++mi) {
        #pragma unroll
        for (int ni = 0; ni < 4; ++ni) {
            #pragma unroll
            for (int r = 0; r < 4; ++r) {
                const long row = m0 + wr * 128 + mi * 16 + q * 4 + r;
                const long col = n0 + wc * 64 + ni * 16 + r16;
                float vv = acc[mi][ni][r];
                if (BIAS_MODE == 1) vv += bias[col];
                if (BIAS_MODE == 2) vv += bias[row];
                if (OUT_MODE == 0) {
                    ((__hip_bfloat16*)outp)[(long)z * sC + row * ldC + col] = __float2bfloat16(vv);
                } else if (OUT_MODE == 1) {
                    ((float*)outp)[(long)z * sC + row * ldC + col] = vv;
                } else if (OUT_MODE == 2) {
                    const long addr = (col >> 8) * (long)(kC * kHW) + row * kHW + (col & 255);
                    ((__hip_bfloat16*)outp)[addr] = __float2bfloat16(vv);
                } else if (OUT_MODE == 3) {
                    const long addr = (col >> 8) * (long)(kC * kHW) + row * kHW + (col & 255);
                    ((float*)outp)[addr] = alpha * vv + resid[addr];
                } else {  // OUT_MODE == 4: PV epilogue
                    const long addr = (long)z * (kC * kHW) + row * kHW + col;
                    const float term = vv + aux1[row] * aux2[(long)z * 256 + col] + bias[row];
                    ((float*)outp)[addr] = alpha * term + resid[addr];
                }
            }
        }
    }
#undef DSA
#undef DSB
#undef MM16
}

template<int OUT_MODE, int BIAS_MODE, int ORDER>
__global__ __launch_bounds__(512, 2) void gemm_q(
    const __hip_bfloat16* __restrict__ A,
    const __hip_bfloat16* __restrict__ Bt,
    void* __restrict__ outp,
    const float* __restrict__ bias,
    const float* __restrict__ resid,
    const float* __restrict__ alphap,
    const float* __restrict__ aux1,
    const float* __restrict__ aux2,
    int M, int N, int K,
    int ldA, int ldB, long sA, long sB, long sC, int ldC)
{
    extern __shared__ char smem[];
    gemm_body<OUT_MODE, BIAS_MODE, ORDER>(A, Bt, outp, bias, resid, alphap,
        aux1, aux2, M, N, K, ldA, ldB, sA, sB, sC, ldC, smem, blockIdx.z);
}

// Dual dispatch: z=0 -> uT = xT*G^T + w1; z=1 -> rv conv = W2*xT^T.
// 640 blocks x 2 z = 1280 = exactly 5 full block-waves (no tail).
__global__ __launch_bounds__(512, 2) void gemm_dual(
    const __hip_bfloat16* __restrict__ xT,
    const __hip_bfloat16* __restrict__ G,
    __hip_bfloat16* __restrict__ uT,
    const float* __restrict__ w1,
    const __hip_bfloat16* __restrict__ W2,
    __hip_bfloat16* __restrict__ rv)
{
    extern __shared__ char smem[];
    if (blockIdx.z == 0) {
        gemm_body<0, 1, 1>(xT, G, uT, w1, nullptr, nullptr, nullptr, nullptr,
            32768, 1280, 1280, 1280, 1280, 0, 0, 0, 1280, smem, 0);
    } else {
        gemm_body<2, 0, 0>(W2, xT, rv, nullptr, nullptr, nullptr, nullptr, nullptr,
            1280, 32768, 1280, 1280, 1280, 0, 0, 0, 0, smem, 0);
    }
}

// K-split x2 weight-product GEMM: z = pair*2 + ks (pair 0: G=WkT*WqT^T,
// pair 1: W2=Wrb*WvT^T), K=640 each, f32 partials Gp[z]. 100 blocks.
__global__ __launch_bounds__(512, 2) void gemm_gsplit(
    const __hip_bfloat16* __restrict__ WkT,
    const __hip_bfloat16* __restrict__ WqT,
    const __hip_bfloat16* __restrict__ Wrb,
    const __hip_bfloat16* __restrict__ WvT,
    float* __restrict__ Gp)
{
    extern __shared__ char smem[];
    const int zz = blockIdx.z;
    const int pair = zz >> 1, ks = zz & 1;
    const __hip_bfloat16* A  = (pair ? Wrb : WkT) + ks * 640;
    const __hip_bfloat16* Bt = (pair ? WvT : WqT) + ks * 640;
    gemm_body<1, 0, 0>(A, Bt, Gp, nullptr, nullptr, nullptr, nullptr, nullptr,
        1280, 1280, 640, 1280, 1280, 0, 0, 1638400, 1280, smem, zz);
}

// G = bf16(Gp0+Gp1), W2 = bf16(Gp2+Gp3)
__global__ __launch_bounds__(256) void reduce_gw(
    const float* __restrict__ Gp,
    __hip_bfloat16* __restrict__ G, __hip_bfloat16* __restrict__ W2)
{
    const long i = ((long)blockIdx.x * 256 + threadIdx.x) * 4;
    const float4 a = *reinterpret_cast<const float4*>(Gp + i);
    const float4 b = *reinterpret_cast<const float4*>(Gp + 1638400 + i);
    G[i + 0] = __float2bfloat16(a.x + b.x);
    G[i + 1] = __float2bfloat16(a.y + b.y);
    G[i + 2] = __float2bfloat16(a.z + b.z);
    G[i + 3] = __float2bfloat16(a.w + b.w);
    const float4 c = *reinterpret_cast<const float4*>(Gp + 2L * 1638400 + i);
    const float4 d = *reinterpret_cast<const float4*>(Gp + 3L * 1638400 + i);
    W2[i + 0] = __float2bfloat16(c.x + d.x);
    W2[i + 1] = __float2bfloat16(c.y + d.y);
    W2[i + 2] = __float2bfloat16(c.z + d.z);
    W2[i + 3] = __float2bfloat16(c.w + d.w);
}

// Scores K-split x2 into SEPARATE buffers (no atomics, no zeroing):
// z = b*2 + kh; sc_kh[b] (256,256) = xT[b,kh*640:] * uT[b,kh*640:]^T.
__global__ __launch_bounds__(512, 2) void gemm_scores(
    const __hip_bfloat16* __restrict__ xT,
    const __hip_bfloat16* __restrict__ uT,
    float* __restrict__ sc)
{
    extern __shared__ char smem[];
    const int b = blockIdx.z >> 1, kh = blockIdx.z & 1;
    const __hip_bfloat16* A  = xT + (long)b * 327680 + kh * 640;
    const __hip_bfloat16* Bt = uT + (long)b * 327680 + kh * 640;
    float* out = sc + (long)kh * 8388608;
    gemm_body<1, 0, 0>(A, Bt, out, nullptr, nullptr, nullptr, nullptr, nullptr,
        256, 256, 640, 1280, 1280, 0, 0, 65536, 256, smem, b);
}

// x (B, C, HW) f32 -> xT (B*HW, C) bf16; fused partial c2s[p] += sum_c x[c][p]*w2[c]
__global__ __launch_bounds__(256) void transpose_x(
    const float* __restrict__ x, __hip_bfloat16* __restrict__ xT,
    const float* __restrict__ w2, float* __restrict__ c2s)
{
    __shared__ float tile[64][65];
    __shared__ float red[4][64];
    const int b = blockIdx.z;
    const int c0 = blockIdx.x * 64;
    const int p0 = blockIdx.y * 64;
    const int tj = threadIdx.x & 63;
    const int ti = threadIdx.x >> 6;
    const float* xb = x + ((long)b * kC + c0) * kHW + p0;
    #pragma unroll
    for (int i = 0; i < 16; ++i) {
        const int c = i * 4 + ti;
        tile[c][tj] = xb[(long)c * kHW + tj];
    }
    __syncthreads();
    __hip_bfloat16* o = xT + ((long)(b * kHW + p0)) * kC + c0;
    #pragma unroll
    for (int i = 0; i < 16; ++i) {
        const int p = i * 4 + ti;
        o[(long)p * kC + tj] = __float2bfloat16(tile[tj][p]);
    }
    float s = 0.0f;
    #pragma unroll
    for (int j = 0; j < 16; ++j)
        s += tile[ti * 16 + j][tj] * w2[c0 + ti * 16 + j];
    red[ti][tj] = s;
    __syncthreads();
    if (ti == 0)
        atomicAdd(&c2s[b * 256 + p0 + tj], red[0][tj] + red[1][tj] + red[2][tj] + red[3][tj]);
}

// z<3: W -> WT bf16 transposed; z==3: Wr -> Wrb bf16 (plain convert)
__global__ __launch_bounds__(256) void transpose_w4(
    const float* __restrict__ Wk, __hip_bfloat16* __restrict__ WkT,
    const float* __restrict__ Wq, __hip_bfloat16* __restrict__ WqT,
    const float* __restrict__ Wv, __hip_bfloat16* __restrict__ WvT,
    const float* __restrict__ Wr, __hip_bfloat16* __restrict__ Wrb)
{
    const int zz = blockIdx.z;
    const float* W = (zz == 0) ? Wk : (zz == 1) ? Wq : (zz == 2) ? Wv : Wr;
    __hip_bfloat16* WT = (zz == 0) ? WkT : (zz == 1) ? WqT : (zz == 2) ? WvT : Wrb;
    __shared__ float tile[64][65];
    const int o0 = blockIdx.x * 64;
    const int c0 = blockIdx.y * 64;
    const int tj = threadIdx.x & 63;
    const int ti = threadIdx.x >> 6;
    #pragma unroll
    for (int i = 0; i < 16; ++i) {
        const int o = i * 4 + ti;
        tile[o][tj] = W[(long)(o0 + o) * kC + c0 + tj];
    }
    __syncthreads();
    if (zz < 3) {
        #pragma unroll
        for (int i = 0; i < 16; ++i) {
            const int c = i * 4 + ti;
            WT[(long)(c0 + c) * kC + o0 + tj] = __float2bfloat16(tile[tj][c]);
        }
    } else {
        #pragma unroll
        for (int i = 0; i < 16; ++i) {
            const int o = i * 4 + ti;
            WT[(long)(o0 + o) * kC + c0 + tj] = __float2bfloat16(tile[o][tj]);
        }
    }
}

__global__ __launch_bounds__(256) void zero_f32(float* __restrict__ p)
{
    reinterpret_cast<float4*>(p)[blockIdx.x * 256 + threadIdx.x] =
        make_float4(0.f, 0.f, 0.f, 0.f);
}

// merged small preproc: 0..19 gemv_col y=0; 20..39 y=1; 40..359 gemv_row; 360 dot
__global__ __launch_bounds__(256) void preproc_small(
    const float* __restrict__ Wk, const float* __restrict__ bq,
    const float* __restrict__ Wq, const float* __restrict__ bk,
    const float* __restrict__ Wr, const float* __restrict__ bv,
    float* __restrict__ w1, float* __restrict__ w2,
    float* __restrict__ wrbv, float* __restrict__ c0out)
{
    const int bidx = blockIdx.x;
    if (bidx < 40) {
        const int y = bidx / 20;
        const int bx = bidx % 20;
        const float* W = y ? Wq : Wk;
        const float* v = y ? bk : bq;
        float* out = y ? w2 : w1;
        const int lj = threadIdx.x & 63;
        const int wid = threadIdx.x >> 6;
        const int c = bx * 64 + lj;
        __shared__ float red[4][64];
        float s = 0.0f;
        for (int o = wid * 320; o < (wid + 1) * 320; ++o)
            s += W[(long)o * kC + c] * v[o];
        red[wid][lj] = s;
        __syncthreads();
        if (wid == 0) out[c] = red[0][lj] + red[1][lj] + red[2][lj] + red[3][lj];
    } else if (bidx < 360) {
        const int bx = bidx - 40;
        const int wid = threadIdx.x >> 6, lj = threadIdx.x & 63;
        const int o = bx * 4 + wid;
        float s = 0.0f;
        #pragma unroll
        for (int j = 0; j < 20; ++j)
            s += Wr[(long)o * kC + j * 64 + lj] * bv[j * 64 + lj];
        #pragma unroll
        for (int off = 32; off > 0; off >>= 1) s += __shfl_down(s, off);
        if (lj == 0) wrbv[o] = s;
    } else {
        __shared__ float red[256];
        const int t_ = threadIdx.x;
        float s = 0.0f;
        for (int j = t_; j < kC; j += 256) s += bk[j] * bq[j];
        red[t_] = s; __syncthreads();
        for (int off = 128; off > 0; off >>= 1) {
            if (t_ < off) red[t_] += red[t_ + off];
            __syncthreads();
        }
        if (t_ == 0) c0out[0] = red[0];
    }
}

// rs[p] = sum_m attn[p*256 + m]
__global__ __launch_bounds__(256) void rowsum_attn(
    const __hip_bfloat16* __restrict__ attn, float* __restrict__ rs)
{
    const int wid = threadIdx.x >> 6, lj = threadIdx.x & 63;
    const long p = (long)blockIdx.x * 4 + wid;
    const ushort4 v = *(const ushort4*)((const char*)attn + p * 512 + lj * 8);
    float s = bf2f(v.x) + bf2f(v.y) + bf2f(v.z) + bf2f(v.w);
    #pragma unroll
    for (int off = 32; off > 0; off >>= 1) s += __shfl_down(s, off);
    if (lj == 0) rs[p] = s;
}

// softmax over BATCH axis; sums two K-split partial buffers + rank-1 corr
__global__ __launch_bounds__(256) void softmax_batch(
    const float* __restrict__ sc, __hip_bfloat16* __restrict__ attn,
    const float* __restrict__ c2s, const float* __restrict__ c0p)
{
    const int pos = blockIdx.x * 256 + threadIdx.x;
    const int mcol = pos & 255;
    const float c0v = c0p[0];
    const float* sc1 = sc + 8388608;
    float m = -3.0e38f, s = 0.0f;
    for (int b = 0; b < kB; ++b) {
        const long i = (long)b * 65536 + pos;
        const float v = sc[i] + sc1[i] + c2s[b * 256 + mcol] + c0v;
        const float mn = fmaxf(m, v);
        s = s * __expf(m - mn) + __expf(v - mn);
        m = mn;
    }
    const float rinv = 1.0f / s;
    for (int b = 0; b < kB; ++b) {
        const long i = (long)b * 65536 + pos;
        const float v = sc[i] + sc1[i] + c2s[b * 256 + mcol] + c0v;
        attn[i] = __float2bfloat16(__expf(v - m) * rinv);
    }
}

extern "C" void kernel_launch(void* const* d_in, const int* in_sizes, int n_in,
                              void* d_out, int out_size, void* d_ws, size_t ws_size,
                              hipStream_t stream)
{
    const float* x  = (const float*)d_in[0];
    const float* Wk = (const float*)d_in[1];
    const float* bk = (const float*)d_in[2];
    const float* Wq = (const float*)d_in[3];
    const float* bq = (const float*)d_in[4];
    const float* Wv = (const float*)d_in[5];
    const float* bv = (const float*)d_in[6];
    const float* Wr = (const float*)d_in[7];
    const float* br = (const float*)d_in[8];
    const float* al = (const float*)d_in[9];

    char* ws = (char*)d_ws;
    __hip_bfloat16* xT   = (__hip_bfloat16*)(ws);               // 83.9MB
    __hip_bfloat16* uT   = (__hip_bfloat16*)(ws + 83886080L);   // 83.9MB
    __hip_bfloat16* attn = (__hip_bfloat16*)(ws + 83886080L);   // aliases uT (dead after scores)
    __hip_bfloat16* rv   = (__hip_bfloat16*)(ws + 167772160L);  // 83.9MB
    float*          Gp   = (float*)(ws + 167772160L);           // aliases rv (dead before dual)
    float*          sc   = (float*)(ws + 251658240L);           // sc0+sc1 = 67.1MB
    __hip_bfloat16* WkT  = (__hip_bfloat16*)(ws + 318767104L);  // 3.28MB each
    __hip_bfloat16* Wrb  = (__hip_bfloat16*)(ws + 322043904L);
    __hip_bfloat16* WqT  = (__hip_bfloat16*)(ws + 325320704L);
    __hip_bfloat16* WvT  = (__hip_bfloat16*)(ws + 328597504L);
    __hip_bfloat16* G    = (__hip_bfloat16*)(ws + 331874304L);
    __hip_bfloat16* W2   = (__hip_bfloat16*)(ws + 335151104L);
    float*          w1   = (float*)(ws + 338427904L);
    float*          w2v  = (float*)(ws + 338433024L);
    float*          wrbv = (float*)(ws + 338438144L);
    float*          c0b  = (float*)(ws + 338443264L);
    float*          c2s  = (float*)(ws + 338443776L);           // 131072B
    float*          rs   = (float*)(ws + 338574848L);           // 131072B

    const int SMEM = 131072;
    hipFuncSetAttribute((const void*)gemm_q<4,0,0>, hipFuncAttributeMaxDynamicSharedMemorySize, SMEM);
    hipFuncSetAttribute((const void*)gemm_dual,   hipFuncAttributeMaxDynamicSharedMemorySize, SMEM);
    hipFuncSetAttribute((const void*)gemm_gsplit, hipFuncAttributeMaxDynamicSharedMemorySize, SMEM);
    hipFuncSetAttribute((const void*)gemm_scores, hipFuncAttributeMaxDynamicSharedMemorySize, SMEM);

    // weight preprocessing
    transpose_w4<<<dim3(20, 20, 4), 256, 0, stream>>>(Wk, WkT, Wq, WqT, Wv, WvT, Wr, Wrb);
    preproc_small<<<361, 256, 0, stream>>>(Wk, bq, Wq, bk, Wr, bv, w1, w2v, wrbv, c0b);
    zero_f32<<<32, 256, 0, stream>>>(c2s);
    transpose_x<<<dim3(20, 4, 128), 256, 0, stream>>>(x, xT, w2v, c2s);

    // G = WkT*WqT^T, W2 = Wrb*WvT^T via K-split x2 (100 blocks), then reduce
    gemm_gsplit<<<dim3(25, 1, 4), 512, SMEM, stream>>>(WkT, WqT, Wrb, WvT, Gp);
    reduce_gw<<<1600, 256, 0, stream>>>(Gp, G, W2);
    // dual: uT = xT*G^T + w1  |  rv = W2*x (conv); 1280 blocks = 5 full waves
    gemm_dual<<<dim3(640, 1, 2), 512, SMEM, stream>>>(xT, G, uT, w1, W2, rv);
    // scores: K-split x2 into sc0/sc1, 256 blocks = full GPU, no atomics
    gemm_scores<<<dim3(1, 1, 256), 512, SMEM, stream>>>(xT, uT, sc);
    softmax_batch<<<256, 256, 0, stream>>>(sc, attn, c2s, c0b);
    rowsum_attn<<<8192, 256, 0, stream>>>(attn, rs);
    // out[b][c][n] = alpha*(sum_m rv[b][c][m]*attn[b][n][m] + wrbv[c]*rs[b,n] + br[c]) + x
    gemm_q<4, 0, 0><<<dim3(5, 1, 128), 512, SMEM, stream>>>(rv, attn, d_out,
        br, x, al, wrbv, rs,
        1280, 256, 256, 256, 256, 327680, 65536, 0, 0);
}

// Round 17
// 483.386 us; speedup vs baseline: 1.0702x; 1.0702x over previous
//
#include <hip/hip_runtime.h>
#include <hip/hip_bf16.h>

typedef __attribute__((ext_vector_type(8))) short bf16x8;
typedef __attribute__((ext_vector_type(4))) float f32x4;

#define GLD16(g, s) __builtin_amdgcn_global_load_lds( \
    (const __attribute__((address_space(1))) void*)(g), \
    (__attribute__((address_space(3))) void*)(s), 16, 0, 0)

#define SBAR() __builtin_amdgcn_sched_barrier(0)
#define WAIT_LGKM(n) do { asm volatile("s_waitcnt lgkmcnt(" #n ")" ::: "memory"); SBAR(); } while (0)

static constexpr int kB  = 128;
static constexpr int kC  = 1280;
static constexpr int kHW = 256;

__device__ __forceinline__ float bf2f(unsigned short u) {
    return __uint_as_float(((unsigned int)u) << 16);
}

// PROVEN structure (R15) minus the redundant bottom barrier:
// BM=BN=256, BK=64; 512 thr = 8 waves (2M x 4N), wave tile 128x64,
// MFMA 16x16x32, 2 LDS slots. Per K-tile: ONE sync point
// {vmcnt(0) + s_barrier} at tile top (covers BOTH tile visibility and
// slot write-after-read -- every wave's ds_reads retired at its
// WAIT_LGKM(0) before reaching the next top barrier), staging burst,
// 4 k-slice phases with P/Q reg double-buffer + counted lgkmcnt, XOR swizzle.
// OUT_MODE: 0=bf16 rowmajor, 1=f32 rowmajor, 2=bf16 conv (col=(b,pix)),
//           3=f32 conv alpha*(acc+bias)+resid, 4=f32 conv-by-z PV epilogue
// BIAS_MODE: 0=none, 1=bias[col], 2=bias[row]
// ORDER: 0 = m-fastest (B operand large), 1 = n-fastest (A operand large)
template<int OUT_MODE, int BIAS_MODE, int ORDER>
__device__ __forceinline__ void gemm_body(
    const __hip_bfloat16* __restrict__ A,
    const __hip_bfloat16* __restrict__ Bt,
    void* __restrict__ outp,
    const float* __restrict__ bias,
    const float* __restrict__ resid,
    const float* __restrict__ alphap,
    const float* __restrict__ aux1,
    const float* __restrict__ aux2,
    int M, int N, int K,
    int ldA, int ldB, long sA, long sB, long sC, int ldC,
    char* smem, int z)
{
    const int t = threadIdx.x;
    const int w = t >> 6, l = t & 63;
    const int q = l >> 4, r16 = l & 15;
    const int wr = w >> 2, wc = w & 3;   // 2M x 4N waves
    const int nbm = M >> 8, nbn = N >> 8;
    const int nwg = nbm * nbn;
    int f = blockIdx.x;
    {   // bijective XCD swizzle (m204)
        const int q8 = nwg >> 3, r8 = nwg & 7;
        const int xcd = f & 7, rank = f >> 3;
        f = (xcd < r8 ? xcd * (q8 + 1) : r8 * (q8 + 1) + (xcd - r8) * q8) + rank;
    }
    long m0, n0;
    if (ORDER == 0) { m0 = (long)(f % nbm) << 8; n0 = (long)(f / nbm) << 8; }
    else            { n0 = (long)(f % nbn) << 8; m0 = (long)(f / nbn) << 8; }
    const char* Azb = (const char*)(A + (long)z * sA);
    const char* Bzb = (const char*)(Bt + (long)z * sB);

    // staging addresses (advance +128B per K-tile); inverse-swizzled source
    const char* pa[4];
    const char* pb[4];
    int ldsd[4];
    #pragma unroll
    for (int i = 0; i < 4; ++i) {
        const int d = i * 8192 + t * 16;
        const int row = d >> 7;
        const int cb = (d & 127) ^ ((row & 7) << 4);
        pa[i] = Azb + ((m0 + row) * (long)ldA) * 2 + cb;
        pb[i] = Bzb + ((n0 + row) * (long)ldB) * 2 + cb;
        ldsd[i] = d;
    }
    auto stage = [&](int slot) {
        char* base = smem + slot * 65536;
        #pragma unroll
        for (int i = 0; i < 4; ++i) GLD16(pa[i], base + ldsd[i]);
        #pragma unroll
        for (int i = 0; i < 4; ++i) GLD16(pb[i], base + 32768 + ldsd[i]);
        #pragma unroll
        for (int i = 0; i < 4; ++i) { pa[i] += 128; pb[i] += 128; }
    };

    // hoisted LDS read offsets
    const int mask = (l & 7) << 4;
    const int cx  = (q << 4) ^ mask;
    int offA[2], offB[2];
    offA[0] = (wr * 128 + r16) * 128 + cx;
    offA[1] = (wr * 128 + r16) * 128 + (cx ^ 64);
    offB[0] = 32768 + (wc * 64 + r16) * 128 + cx;
    offB[1] = 32768 + (wc * 64 + r16) * 128 + (cx ^ 64);

#define DSA(dst, bs_, mih, kk) do { const char* p_ = (bs_) + offA[kk] + (mih) * 8192; \
    dst[0] = *(const bf16x8*)(p_);        dst[1] = *(const bf16x8*)(p_ + 2048); \
    dst[2] = *(const bf16x8*)(p_ + 4096); dst[3] = *(const bf16x8*)(p_ + 6144); } while (0)
#define DSB(dst, bs_, kk) do { const char* p_ = (bs_) + offB[kk]; \
    dst[0] = *(const bf16x8*)(p_);        dst[1] = *(const bf16x8*)(p_ + 2048); \
    dst[2] = *(const bf16x8*)(p_ + 4096); dst[3] = *(const bf16x8*)(p_ + 6144); } while (0)
#define MM16(ar, br, mih) do { __builtin_amdgcn_s_setprio(1); \
    _Pragma("unroll") for (int j = 0; j < 4; ++j) \
    _Pragma("unroll") for (int ni = 0; ni < 4; ++ni) \
        acc[(mih) * 4 + j][ni] = __builtin_amdgcn_mfma_f32_16x16x32_bf16( \
            ar[j], br[ni], acc[(mih) * 4 + j][ni], 0, 0, 0); \
    __builtin_amdgcn_s_setprio(0); SBAR(); } while (0)

    f32x4 acc[8][4] = {};
    const int nK = K >> 6;
    stage(0);

    for (int tk = 0; tk < nK; ++tk) {
        const int s = tk & 1;
        // ONE sync point per tile: own staging drained + collective barrier.
        // Covers (a) tile-t visibility (all waves drained own loads before
        // barrier) and (b) slot-s write-after-read (all waves' tile-(t-1)
        // ds_reads retired at their WAIT_LGKM(0) before reaching here).
        asm volatile("s_waitcnt vmcnt(0)" ::: "memory");
        SBAR();
        __builtin_amdgcn_s_barrier();
        SBAR();
        if (tk + 1 < nK) stage(s ^ 1);
        SBAR();

        const char* bs_ = smem + s * 65536;
        bf16x8 aP[4], bP[4], aQ[4], bQ[4];
        DSB(bP, bs_, 0); DSA(aP, bs_, 0, 0);
        DSA(aQ, bs_, 1, 0);
        WAIT_LGKM(4);  MM16(aP, bP, 0);
        DSB(bQ, bs_, 1); DSA(aP, bs_, 0, 1);
        WAIT_LGKM(8);  MM16(aQ, bP, 1);
        DSA(aQ, bs_, 1, 1);
        WAIT_LGKM(4);  MM16(aP, bQ, 0);
        WAIT_LGKM(0);  MM16(aQ, bQ, 1);
        // (bottom barrier removed -- proven redundant, see header comment)
    }

    const float alpha = (OUT_MODE >= 3) ? alphap[0] : 0.0f;
    #pragma unroll
    for (int mi = 0; mi < 8; ++mi) {
        #pragma unroll
        for (int ni = 0; ni < 4; ++ni) {
            #pragma unroll
            for (int r = 0; r < 4; ++r) {
                const long row = m0 + wr * 128 + mi * 16 + q * 4 + r;
                const long col = n0 + wc * 64 + ni * 16 + r16;
                float vv = acc[mi][ni][r];
                if (BIAS_MODE == 1) vv += bias[col];
                if (BIAS_MODE == 2) vv += bias[row];
                if (OUT_MODE == 0) {
                    ((__hip_bfloat16*)outp)[(long)z * sC + row * ldC + col] = __float2bfloat16(vv);
                } else if (OUT_MODE == 1) {
                    ((float*)outp)[(long)z * sC + row * ldC + col] = vv;
                } else if (OUT_MODE == 2) {
                    const long addr = (col >> 8) * (long)(kC * kHW) + row * kHW + (col & 255);
                    ((__hip_bfloat16*)outp)[addr] = __float2bfloat16(vv);
                } else if (OUT_MODE == 3) {
                    const long addr = (col >> 8) * (long)(kC * kHW) + row * kHW + (col & 255);
                    ((float*)outp)[addr] = alpha * vv + resid[addr];
                } else {  // OUT_MODE == 4: PV epilogue
                    const long addr = (long)z * (kC * kHW) + row * kHW + col;
                    const float term = vv + aux1[row] * aux2[(long)z * 256 + col] + bias[row];
                    ((float*)outp)[addr] = alpha * term + resid[addr];
                }
            }
        }
    }
#undef DSA
#undef DSB
#undef MM16
}

template<int OUT_MODE, int BIAS_MODE, int ORDER>
__global__ __launch_bounds__(512, 2) void gemm_q(
    const __hip_bfloat16* __restrict__ A,
    const __hip_bfloat16* __restrict__ Bt,
    void* __restrict__ outp,
    const float* __restrict__ bias,
    const float* __restrict__ resid,
    const float* __restrict__ alphap,
    const float* __restrict__ aux1,
    const float* __restrict__ aux2,
    int M, int N, int K,
    int ldA, int ldB, long sA, long sB, long sC, int ldC)
{
    extern __shared__ char smem[];
    gemm_body<OUT_MODE, BIAS_MODE, ORDER>(A, Bt, outp, bias, resid, alphap,
        aux1, aux2, M, N, K, ldA, ldB, sA, sB, sC, ldC, smem, blockIdx.z);
}

// Dual dispatch: z=0 -> uT = xT*G^T + w1; z=1 -> rv conv = W2*xT^T.
// 640 blocks x 2 z = 1280 = exactly 5 full block-waves (no tail).
__global__ __launch_bounds__(512, 2) void gemm_dual(
    const __hip_bfloat16* __restrict__ xT,
    const __hip_bfloat16* __restrict__ G,
    __hip_bfloat16* __restrict__ uT,
    const float* __restrict__ w1,
    const __hip_bfloat16* __restrict__ W2,
    __hip_bfloat16* __restrict__ rv)
{
    extern __shared__ char smem[];
    if (blockIdx.z == 0) {
        gemm_body<0, 1, 1>(xT, G, uT, w1, nullptr, nullptr, nullptr, nullptr,
            32768, 1280, 1280, 1280, 1280, 0, 0, 0, 1280, smem, 0);
    } else {
        gemm_body<2, 0, 0>(W2, xT, rv, nullptr, nullptr, nullptr, nullptr, nullptr,
            1280, 32768, 1280, 1280, 1280, 0, 0, 0, 0, smem, 0);
    }
}

// K-split x2 weight-product GEMM: z = pair*2 + ks (pair 0: G=WkT*WqT^T,
// pair 1: W2=Wrb*WvT^T), K=640 each, f32 partials Gp[z]. 100 blocks.
__global__ __launch_bounds__(512, 2) void gemm_gsplit(
    const __hip_bfloat16* __restrict__ WkT,
    const __hip_bfloat16* __restrict__ WqT,
    const __hip_bfloat16* __restrict__ Wrb,
    const __hip_bfloat16* __restrict__ WvT,
    float* __restrict__ Gp)
{
    extern __shared__ char smem[];
    const int zz = blockIdx.z;
    const int pair = zz >> 1, ks = zz & 1;
    const __hip_bfloat16* A  = (pair ? Wrb : WkT) + ks * 640;
    const __hip_bfloat16* Bt = (pair ? WvT : WqT) + ks * 640;
    gemm_body<1, 0, 0>(A, Bt, Gp, nullptr, nullptr, nullptr, nullptr, nullptr,
        1280, 1280, 640, 1280, 1280, 0, 0, 1638400, 1280, smem, zz);
}

// G = bf16(Gp0+Gp1), W2 = bf16(Gp2+Gp3)
__global__ __launch_bounds__(256) void reduce_gw(
    const float* __restrict__ Gp,
    __hip_bfloat16* __restrict__ G, __hip_bfloat16* __restrict__ W2)
{
    const long i = ((long)blockIdx.x * 256 + threadIdx.x) * 4;
    const float4 a = *reinterpret_cast<const float4*>(Gp + i);
    const float4 b = *reinterpret_cast<const float4*>(Gp + 1638400 + i);
    G[i + 0] = __float2bfloat16(a.x + b.x);
    G[i + 1] = __float2bfloat16(a.y + b.y);
    G[i + 2] = __float2bfloat16(a.z + b.z);
    G[i + 3] = __float2bfloat16(a.w + b.w);
    const float4 c = *reinterpret_cast<const float4*>(Gp + 2L * 1638400 + i);
    const float4 d = *reinterpret_cast<const float4*>(Gp + 3L * 1638400 + i);
    W2[i + 0] = __float2bfloat16(c.x + d.x);
    W2[i + 1] = __float2bfloat16(c.y + d.y);
    W2[i + 2] = __float2bfloat16(c.z + d.z);
    W2[i + 3] = __float2bfloat16(c.w + d.w);
}

// Scores K-split x2 into SEPARATE buffers (no atomics, no zeroing):
// z = b*2 + kh; sc_kh[b] (256,256) = xT[b,kh*640:] * uT[b,kh*640:]^T.
__global__ __launch_bounds__(512, 2) void gemm_scores(
    const __hip_bfloat16* __restrict__ xT,
    const __hip_bfloat16* __restrict__ uT,
    float* __restrict__ sc)
{
    extern __shared__ char smem[];
    const int b = blockIdx.z >> 1, kh = blockIdx.z & 1;
    const __hip_bfloat16* A  = xT + (long)b * 327680 + kh * 640;
    const __hip_bfloat16* Bt = uT + (long)b * 327680 + kh * 640;
    float* out = sc + (long)kh * 8388608;
    gemm_body<1, 0, 0>(A, Bt, out, nullptr, nullptr, nullptr, nullptr, nullptr,
        256, 256, 640, 1280, 1280, 0, 0, 65536, 256, smem, b);
}

// x (B, C, HW) f32 -> xT (B*HW, C) bf16; fused partial c2s[p] += sum_c x[c][p]*w2[c]
__global__ __launch_bounds__(256) void transpose_x(
    const float* __restrict__ x, __hip_bfloat16* __restrict__ xT,
    const float* __restrict__ w2, float* __restrict__ c2s)
{
    __shared__ float tile[64][65];
    __shared__ float red[4][64];
    const int b = blockIdx.z;
    const int c0 = blockIdx.x * 64;
    const int p0 = blockIdx.y * 64;
    const int tj = threadIdx.x & 63;
    const int ti = threadIdx.x >> 6;
    const float* xb = x + ((long)b * kC + c0) * kHW + p0;
    #pragma unroll
    for (int i = 0; i < 16; ++i) {
        const int c = i * 4 + ti;
        tile[c][tj] = xb[(long)c * kHW + tj];
    }
    __syncthreads();
    __hip_bfloat16* o = xT + ((long)(b * kHW + p0)) * kC + c0;
    #pragma unroll
    for (int i = 0; i < 16; ++i) {
        const int p = i * 4 + ti;
        o[(long)p * kC + tj] = __float2bfloat16(tile[tj][p]);
    }
    float s = 0.0f;
    #pragma unroll
    for (int j = 0; j < 16; ++j)
        s += tile[ti * 16 + j][tj] * w2[c0 + ti * 16 + j];
    red[ti][tj] = s;
    __syncthreads();
    if (ti == 0)
        atomicAdd(&c2s[b * 256 + p0 + tj], red[0][tj] + red[1][tj] + red[2][tj] + red[3][tj]);
}

// z<3: W -> WT bf16 transposed; z==3: Wr -> Wrb bf16 (plain convert)
__global__ __launch_bounds__(256) void transpose_w4(
    const float* __restrict__ Wk, __hip_bfloat16* __restrict__ WkT,
    const float* __restrict__ Wq, __hip_bfloat16* __restrict__ WqT,
    const float* __restrict__ Wv, __hip_bfloat16* __restrict__ WvT,
    const float* __restrict__ Wr, __hip_bfloat16* __restrict__ Wrb)
{
    const int zz = blockIdx.z;
    const float* W = (zz == 0) ? Wk : (zz == 1) ? Wq : (zz == 2) ? Wv : Wr;
    __hip_bfloat16* WT = (zz == 0) ? WkT : (zz == 1) ? WqT : (zz == 2) ? WvT : Wrb;
    __shared__ float tile[64][65];
    const int o0 = blockIdx.x * 64;
    const int c0 = blockIdx.y * 64;
    const int tj = threadIdx.x & 63;
    const int ti = threadIdx.x >> 6;
    #pragma unroll
    for (int i = 0; i < 16; ++i) {
        const int o = i * 4 + ti;
        tile[o][tj] = W[(long)(o0 + o) * kC + c0 + tj];
    }
    __syncthreads();
    if (zz < 3) {
        #pragma unroll
        for (int i = 0; i < 16; ++i) {
            const int c = i * 4 + ti;
            WT[(long)(c0 + c) * kC + o0 + tj] = __float2bfloat16(tile[tj][c]);
        }
    } else {
        #pragma unroll
        for (int i = 0; i < 16; ++i) {
            const int o = i * 4 + ti;
            WT[(long)(o0 + o) * kC + c0 + tj] = __float2bfloat16(tile[o][tj]);
        }
    }
}

// merged small preproc: 0..19 gemv_col y=0; 20..39 y=1; 40..359 gemv_row;
// 360 dot_k; 361..392 zero c2s
__global__ __launch_bounds__(256) void preproc_small(
    const float* __restrict__ Wk, const float* __restrict__ bq,
    const float* __restrict__ Wq, const float* __restrict__ bk,
    const float* __restrict__ Wr, const float* __restrict__ bv,
    float* __restrict__ w1, float* __restrict__ w2,
    float* __restrict__ wrbv, float* __restrict__ c0out,
    float* __restrict__ c2s)
{
    const int bidx = blockIdx.x;
    if (bidx < 40) {
        const int y = bidx / 20;
        const int bx = bidx % 20;
        const float* W = y ? Wq : Wk;
        const float* v = y ? bk : bq;
        float* out = y ? w2 : w1;
        const int lj = threadIdx.x & 63;
        const int wid = threadIdx.x >> 6;
        const int c = bx * 64 + lj;
        __shared__ float red[4][64];
        float s = 0.0f;
        for (int o = wid * 320; o < (wid + 1) * 320; ++o)
            s += W[(long)o * kC + c] * v[o];
        red[wid][lj] = s;
        __syncthreads();
        if (wid == 0) out[c] = red[0][lj] + red[1][lj] + red[2][lj] + red[3][lj];
    } else if (bidx < 360) {
        const int bx = bidx - 40;
        const int wid = threadIdx.x >> 6, lj = threadIdx.x & 63;
        const int o = bx * 4 + wid;
        float s = 0.0f;
        #pragma unroll
        for (int j = 0; j < 20; ++j)
            s += Wr[(long)o * kC + j * 64 + lj] * bv[j * 64 + lj];
        #pragma unroll
        for (int off = 32; off > 0; off >>= 1) s += __shfl_down(s, off);
        if (lj == 0) wrbv[o] = s;
    } else if (bidx == 360) {
        __shared__ float red[256];
        const int t_ = threadIdx.x;
        float s = 0.0f;
        for (int j = t_; j < kC; j += 256) s += bk[j] * bq[j];
        red[t_] = s; __syncthreads();
        for (int off = 128; off > 0; off >>= 1) {
            if (t_ < off) red[t_] += red[t_ + off];
            __syncthreads();
        }
        if (t_ == 0) c0out[0] = red[0];
    } else {
        reinterpret_cast<float4*>(c2s)[(long)(bidx - 361) * 256 + threadIdx.x] =
            make_float4(0.f, 0.f, 0.f, 0.f);
    }
}

// rs[p] = sum_m attn[p*256 + m]
__global__ __launch_bounds__(256) void rowsum_attn(
    const __hip_bfloat16* __restrict__ attn, float* __restrict__ rs)
{
    const int wid = threadIdx.x >> 6, lj = threadIdx.x & 63;
    const long p = (long)blockIdx.x * 4 + wid;
    const ushort4 v = *(const ushort4*)((const char*)attn + p * 512 + lj * 8);
    float s = bf2f(v.x) + bf2f(v.y) + bf2f(v.z) + bf2f(v.w);
    #pragma unroll
    for (int off = 32; off > 0; off >>= 1) s += __shfl_down(s, off);
    if (lj == 0) rs[p] = s;
}

// softmax over BATCH axis; sums two K-split partial buffers + rank-1 corr
__global__ __launch_bounds__(256) void softmax_batch(
    const float* __restrict__ sc, __hip_bfloat16* __restrict__ attn,
    const float* __restrict__ c2s, const float* __restrict__ c0p)
{
    const int pos = blockIdx.x * 256 + threadIdx.x;
    const int mcol = pos & 255;
    const float c0v = c0p[0];
    const float* sc1 = sc + 8388608;
    float m = -3.0e38f, s = 0.0f;
    for (int b = 0; b < kB; ++b) {
        const long i = (long)b * 65536 + pos;
        const float v = sc[i] + sc1[i] + c2s[b * 256 + mcol] + c0v;
        const float mn = fmaxf(m, v);
        s = s * __expf(m - mn) + __expf(v - mn);
        m = mn;
    }
    const float rinv = 1.0f / s;
    for (int b = 0; b < kB; ++b) {
        const long i = (long)b * 65536 + pos;
        const float v = sc[i] + sc1[i] + c2s[b * 256 + mcol] + c0v;
        attn[i] = __float2bfloat16(__expf(v - m) * rinv);
    }
}

extern "C" void kernel_launch(void* const* d_in, const int* in_sizes, int n_in,
                              void* d_out, int out_size, void* d_ws, size_t ws_size,
                              hipStream_t stream)
{
    const float* x  = (const float*)d_in[0];
    const float* Wk = (const float*)d_in[1];
    const float* bk = (const float*)d_in[2];
    const float* Wq = (const float*)d_in[3];
    const float* bq = (const float*)d_in[4];
    const float* Wv = (const float*)d_in[5];
    const float* bv = (const float*)d_in[6];
    const float* Wr = (const float*)d_in[7];
    const float* br = (const float*)d_in[8];
    const float* al = (const float*)d_in[9];

    char* ws = (char*)d_ws;
    __hip_bfloat16* xT   = (__hip_bfloat16*)(ws);               // 83.9MB
    __hip_bfloat16* uT   = (__hip_bfloat16*)(ws + 83886080L);   // 83.9MB
    __hip_bfloat16* attn = (__hip_bfloat16*)(ws + 83886080L);   // aliases uT (dead after scores)
    __hip_bfloat16* rv   = (__hip_bfloat16*)(ws + 167772160L);  // 83.9MB
    float*          Gp   = (float*)(ws + 167772160L);           // aliases rv (dead before dual)
    float*          sc   = (float*)(ws + 251658240L);           // sc0+sc1 = 67.1MB
    __hip_bfloat16* WkT  = (__hip_bfloat16*)(ws + 318767104L);  // 3.28MB each
    __hip_bfloat16* Wrb  = (__hip_bfloat16*)(ws + 322043904L);
    __hip_bfloat16* WqT  = (__hip_bfloat16*)(ws + 325320704L);
    __hip_bfloat16* WvT  = (__hip_bfloat16*)(ws + 328597504L);
    __hip_bfloat16* G    = (__hip_bfloat16*)(ws + 331874304L);
    __hip_bfloat16* W2   = (__hip_bfloat16*)(ws + 335151104L);
    float*          w1   = (float*)(ws + 338427904L);
    float*          w2v  = (float*)(ws + 338433024L);
    float*          wrbv = (float*)(ws + 338438144L);
    float*          c0b  = (float*)(ws + 338443264L);
    float*          c2s  = (float*)(ws + 338443776L);           // 131072B
    float*          rs   = (float*)(ws + 338574848L);           // 131072B

    const int SMEM = 131072;
    hipFuncSetAttribute((const void*)gemm_q<4,0,0>, hipFuncAttributeMaxDynamicSharedMemorySize, SMEM);
    hipFuncSetAttribute((const void*)gemm_dual,   hipFuncAttributeMaxDynamicSharedMemorySize, SMEM);
    hipFuncSetAttribute((const void*)gemm_gsplit, hipFuncAttributeMaxDynamicSharedMemorySize, SMEM);
    hipFuncSetAttribute((const void*)gemm_scores, hipFuncAttributeMaxDynamicSharedMemorySize, SMEM);

    // weight preprocessing (zero_c2s folded into preproc_small blocks 361..392)
    transpose_w4<<<dim3(20, 20, 4), 256, 0, stream>>>(Wk, WkT, Wq, WqT, Wv, WvT, Wr, Wrb);
    preproc_small<<<393, 256, 0, stream>>>(Wk, bq, Wq, bk, Wr, bv, w1, w2v, wrbv, c0b, c2s);
    transpose_x<<<dim3(20, 4, 128), 256, 0, stream>>>(x, xT, w2v, c2s);

    // G = WkT*WqT^T, W2 = Wrb*WvT^T via K-split x2 (100 blocks), then reduce
    gemm_gsplit<<<dim3(25, 1, 4), 512, SMEM, stream>>>(WkT, WqT, Wrb, WvT, Gp);
    reduce_gw<<<1600, 256, 0, stream>>>(Gp, G, W2);
    // dual: uT = xT*G^T + w1  |  rv = W2*x (conv); 1280 blocks = 5 full waves
    gemm_dual<<<dim3(640, 1, 2), 512, SMEM, stream>>>(xT, G, uT, w1, W2, rv);
    // scores: K-split x2 into sc0/sc1, 256 blocks = full GPU, no atomics
    gemm_scores<<<dim3(1, 1, 256), 512, SMEM, stream>>>(xT, uT, sc);
    softmax_batch<<<256, 256, 0, stream>>>(sc, attn, c2s, c0b);
    rowsum_attn<<<8192, 256, 0, stream>>>(attn, rs);
    // out[b][c][n] = alpha*(sum_m rv[b][c][m]*attn[b][n][m] + wrbv[c]*rs[b,n] + br[c]) + x
    gemm_q<4, 0, 0><<<dim3(5, 1, 128), 512, SMEM, stream>>>(rv, attn, d_out,
        br, x, al, wrbv, rs,
        1280, 256, 256, 256, 256, 327680, 65536, 0, 0);
}